// Round 7
// baseline (149.952 us; speedup 1.0000x reference)
//
#include <hip/hip_runtime.h>
#include <math.h>

#define NC 512
#define NB 2
#define M 1024
#define KS 24
#define NA 60
#define CO 128
#define CELLS 1440
#define CCELLS 480
#define NTOT 30720.0f
// log2(e)/SIGMA, SIGMA=0.08
#define LSCALE 18.033688011112043f
#define R2 0.16f
#define NSLOT 32

#define FEAT_OFF 3072
#define ANCH_OFF (3072 + 7864320)

// k_out2 tiling
#define WLP 1444           // padded LDS row stride (words); 1444%32=4 -> bank-balanced
#define TILE_N 8
#define BLK_C 8
#define BLK_N 32

__device__ __forceinline__ float dot4acc(float s, float4 w, float4 v) {
    return fmaf(w.x, v.x, fmaf(w.y, v.y, fmaf(w.z, v.z, fmaf(w.w, v.w, s))));
}

// ---------- K1: wts chunk (20 a's = 480 cells) + fused feature-stats ----------
// grid 3072 = (bn, chunk); accum[b][slot][c][2] gets atomic {sum f, sum f^2}.
__launch_bounds__(256)
__global__ void k_wts(const float* __restrict__ frag, const float* __restrict__ clouds,
                      const float* __restrict__ kernels, const float* __restrict__ W,
                      float* __restrict__ wts, float* __restrict__ accum) {
    int bx = blockIdx.x;
    int chunk = bx % 3;
    int bn = bx / 3;
    int b = bn >> 9, n = bn & (NC - 1);
    int tid = threadIdx.x, wave = tid >> 6, lane = tid & 63;
    __shared__ float4 spl[M];
    __shared__ int wcnt[16];
    __shared__ __align__(16) float swl[512];  // chunk wts (480 used)

    // per-thread cell constants
    int lc0 = tid, lc1 = tid + 256;
    float4 kc0, kc1;
    {
        int cells[2] = {chunk * CCELLS + lc0, chunk * CCELLS + lc1};
        bool vld[2] = {true, lc1 < CCELLS};
        float4* kcs[2] = {&kc0, &kc1};
        #pragma unroll
        for (int q = 0; q < 2; ++q) {
            if (vld[q]) {
                int cell = cells[q];
                int a = cell / KS, k = cell - a * KS;
                const float* kp = kernels + (size_t)(k * NA + a) * 3;
                float kx = kp[0], ky = kp[1], kz = kp[2];
                float k2 = kx * kx + ky * ky + kz * kz;
                *kcs[q] = make_float4(kx * (2.0f * LSCALE), ky * (2.0f * LSCALE),
                                      kz * (2.0f * LSCALE), -k2 * LSCALE);
            } else {
                *kcs[q] = make_float4(0.f, 0.f, 0.f, -1e30f);  // hw exp2 -> 0
            }
        }
    }

    float cx = clouds[b * 3 * NC + n];
    float cy = clouds[b * 3 * NC + NC + n];
    float cz = clouds[b * 3 * NC + 2 * NC + n];

    float dx[4], dy[4], dz[4], ei[4];
    int pos[4];
    bool pr[4];
    unsigned long long lmask = (1ull << lane) - 1ull;
    #pragma unroll
    for (int j = 0; j < 4; ++j) {
        int m = tid + j * 256;
        dx[j] = frag[3 * m]     - cx;
        dy[j] = frag[3 * m + 1] - cy;
        dz[j] = frag[3 * m + 2] - cz;
        // match jnp's non-contracted sum of squares (mask boundary exactness)
        float s = __fmul_rn(dx[j], dx[j]);
        s = __fadd_rn(s, __fmul_rn(dy[j], dy[j]));
        s = __fadd_rn(s, __fmul_rn(dz[j], dz[j]));
        pr[j] = s < R2;
        ei[j] = __builtin_amdgcn_exp2f(-s * LSCALE);
        unsigned long long mk = __ballot(pr[j]);
        pos[j] = __popcll(mk & lmask);
        if (lane == 0) wcnt[j * 4 + wave] = __popcll(mk);
    }
    __syncthreads();
    int run = 0, base[4];
    #pragma unroll
    for (int t2 = 0; t2 < 16; ++t2) {
        if ((t2 & 3) == wave) base[t2 >> 2] = run;
        run += wcnt[t2];
    }
    int cnt = run;
    #pragma unroll
    for (int j = 0; j < 4; ++j)
        if (pr[j]) spl[base[j] + pos[j]] = make_float4(dx[j], dy[j], dz[j], ei[j]);
    __syncthreads();

    float acc0 = 0.f, acc1 = 0.f;
    #pragma unroll 4
    for (int i = 0; i < cnt; ++i) {
        float4 p = spl[i];  // broadcast ds_read_b128; p.w = exp2(-d2*L)
        float a0 = fmaf(p.x, kc0.x, fmaf(p.y, kc0.y, fmaf(p.z, kc0.z, kc0.w)));
        float a1 = fmaf(p.x, kc1.x, fmaf(p.y, kc1.y, fmaf(p.z, kc1.z, kc1.w)));
        acc0 = fmaf(__builtin_amdgcn_exp2f(a0), p.w, acc0);
        acc1 = fmaf(__builtin_amdgcn_exp2f(a1), p.w, acc1);
    }

    float inv = 1.0f / (float)(cnt + 1);
    float w0 = acc0 * inv, w1 = acc1 * inv;
    float* wrow = wts + (size_t)bn * CELLS + chunk * CCELLS;
    wrow[lc0] = w0;
    swl[lc0] = w0;
    if (lc1 < CCELLS) { wrow[lc1] = w1; swl[lc1] = w1; }
    __syncthreads();

    // fused feature stats over this chunk's 20 a's: f = W[c]·v[a], accumulate
    int c = tid >> 1, ah = tid & 1;
    float4 wr[6];
    {
        const float4* W4 = (const float4*)(W + c * KS);
        #pragma unroll
        for (int j = 0; j < 6; ++j) wr[j] = W4[j];
    }
    float fs = 0.f, fs2 = 0.f;
    #pragma unroll
    for (int i = 0; i < 10; ++i) {
        const float4* v4 = (const float4*)(swl + (ah * 10 + i) * KS);
        float f = 0.f;
        #pragma unroll
        for (int j = 0; j < 6; ++j) f = dot4acc(f, wr[j], v4[j]);
        fs += f;
        fs2 = fmaf(f, f, fs2);
    }
    fs  += __shfl_xor(fs, 1);
    fs2 += __shfl_xor(fs2, 1);
    if (ah == 0) {
        int slot = bx & (NSLOT - 1);
        float* ap = accum + (((size_t)(b * NSLOT + slot) * CO + c) * 2);
        atomicAdd(&ap[0], fs);
        atomicAdd(&ap[1], fs2);
    }
}

// ---------- K2: (b, 8c, 32n)-tiled output; contiguous aligned 1920B stores ----------
// grid 512. XCD-affinity: b from (bid&7)>>2 so each XCD's L2 streams one b's wts.
__launch_bounds__(256)
__global__ void k_out(const float* __restrict__ wts, const float* __restrict__ W,
                      const float* __restrict__ accum, const float* __restrict__ clouds,
                      const float* __restrict__ anchors, float* __restrict__ out) {
    int bid = blockIdx.x;
    int xcd = bid & 7, grp = bid >> 3;
    int b   = xcd >> 2;
    int sub = (xcd & 3) * 64 + grp;   // 0..255 within this b
    int cg  = sub >> 4;               // 16 c-groups of 8
    int nr  = sub & 15;               // 16 n-ranges of 32
    int tid = threadIdx.x;

    __shared__ __align__(16) float wl[TILE_N * WLP];   // 46,208 B
    __shared__ __align__(16) float fl[BLK_C * TILE_N * NA]; // 15,360 B
    __shared__ float4 sred[128];
    __shared__ float2 sst[BLK_C];

    // passthrough outputs
    if (bid < 12) {
        int i = bid * 256 + tid;
        out[i] = clouds[i];
    } else if (bid < 15) {
        int i = (bid - 12) * 256 + tid;
        if (i < 540) out[ANCH_OFF + i] = anchors[i];
    }

    // stats partial loads: slot-major, 4 c-pairs of this c-group
    if (tid < 128) {
        int slot = tid >> 2, cpl = tid & 3;
        sred[tid] = ((const float4*)accum)[((size_t)(b * NSLOT + slot)) * 64 + cg * 4 + cpl];
    }

    // stage tile 0
    const float* wbase = wts + ((size_t)(b * NC + nr * BLK_N)) * CELLS;
    {
        #pragma unroll
        for (int j = 0; j < 12; ++j) {
            int idx = j * 256 + tid;
            if (idx < 720 * 4) {
                int r = idx / 360, cw = idx - r * 360;
                float4 v = ((const float4*)(wbase + (size_t)r * CELLS))[cw];
                ((float4*)(wl + r * WLP))[cw] = v;
            }
        }
    }
    __syncthreads();

    if (tid < 4) {  // finalize stats for c = cg*8 + tid*2, +1
        float4 r = make_float4(0.f, 0.f, 0.f, 0.f);
        #pragma unroll
        for (int s = 0; s < NSLOT; ++s) {
            float4 v = sred[s * 4 + tid];
            r.x += v.x; r.y += v.y; r.z += v.z; r.w += v.w;
        }
        const float invN = 1.0f / NTOT;
        float mu0 = r.x * invN;
        float var0 = fmaxf(fmaf(-mu0, mu0, r.y * invN), 0.f);
        float mu1 = r.z * invN;
        float var1 = fmaxf(fmaf(-mu1, mu1, r.w * invN), 0.f);
        sst[tid * 2]     = make_float2(mu0, rsqrtf(var0 + 1e-5f));
        sst[tid * 2 + 1] = make_float2(mu1, rsqrtf(var1 + 1e-5f));
    }

    // per-thread role: c_loc (8) x { np (8) x aq (4) -> 15 a each }
    int c_loc = tid >> 5, t5 = tid & 31;
    int np = t5 >> 2, aq = t5 & 3;
    int c = cg * BLK_C + c_loc;
    float4 wr[6];
    {
        const float4* W4 = (const float4*)(W + c * KS);
        #pragma unroll
        for (int j = 0; j < 6; ++j) wr[j] = W4[j];
    }
    __syncthreads();
    float2 st = sst[c_loc];

    for (int t = 0; t < 4; ++t) {
        // compute: f for (c_loc, np, 15 a's) from wl
        const float* vrow = wl + np * WLP;
        #pragma unroll
        for (int i = 0; i < 15; ++i) {
            int a = aq * 15 + i;
            const float4* v4 = (const float4*)(vrow + a * KS);
            float f = 0.f;
            #pragma unroll
            for (int j = 0; j < 6; ++j) f = dot4acc(f, wr[j], v4[j]);
            fl[(c_loc * TILE_N + np) * NA + a] = fmaxf((f - st.x) * st.y, 0.f);
        }
        __syncthreads();
        // prefetch next tile into wl (safe: compute done), then store fl
        if (t < 3) {
            #pragma unroll
            for (int j = 0; j < 12; ++j) {
                int idx = j * 256 + tid;
                if (idx < 720 * 4) {
                    int r = idx / 360, cw = idx - r * 360;
                    float4 v = ((const float4*)(wbase + (size_t)((t + 1) * TILE_N + r) * CELLS))[cw];
                    ((float4*)(wl + r * WLP))[cw] = v;
                }
            }
        }
        {
            // store 8 c x 1920 B contiguous aligned runs
            const float4* fl4 = (const float4*)fl;
            int n0 = nr * BLK_N + t * TILE_N;
            float* obase = out + FEAT_OFF + ((size_t)(b * CO + c) * NC + n0) * NA;
            #pragma unroll
            for (int q = 0; q < 4; ++q) {
                int fi = t5 + q * 32;
                if (fi < 120) {
                    float4 v = fl4[c_loc * 120 + fi];
                    ((float4*)obase)[fi] = v;
                }
            }
        }
        if (t < 3) __syncthreads();
    }
}

extern "C" void kernel_launch(void* const* d_in, const int* in_sizes, int n_in,
                              void* d_out, int out_size, void* d_ws, size_t ws_size,
                              hipStream_t stream) {
    const float* frag    = (const float*)d_in[0];
    const float* clouds  = (const float*)d_in[1];
    const float* kernels = (const float*)d_in[2];
    const float* W       = (const float*)d_in[3];
    const float* anchors = (const float*)d_in[4];
    float* out = (float*)d_out;

    char* ws = (char*)d_ws;
    float* wts   = (float*)(ws);                 // 1024*1440*4 = 5,898,240 B
    float* accum = (float*)(ws + 5898240);       // 2*32*128*2*4 = 65,536 B

    hipMemsetAsync(accum, 0, 2 * NSLOT * CO * 2 * sizeof(float), stream);
    k_wts<<<3 * NB * NC, 256, 0, stream>>>(frag, clouds, kernels, W, wts, accum);
    k_out<<<512, 256, 0, stream>>>(wts, W, accum, clouds, anchors, out);
}

// Round 8
// 138.196 us; speedup vs baseline: 1.0851x; 1.0851x over previous
//
#include <hip/hip_runtime.h>
#include <math.h>

#define NC 512
#define NB 2
#define M 1024
#define KS 24
#define NA 60
#define CO 128
#define CELLS 1440
#define CCELLS 480
#define NTOT 30720.0f
// log2(e)/SIGMA, SIGMA=0.08
#define LSCALE 18.033688011112043f
#define R2 0.16f
#define NSLOT 32

#define FEAT_OFF 3072
#define ANCH_OFF (3072 + 7864320)
#define FLP 61   // padded fl stride

__device__ __forceinline__ float dot4acc(float s, float4 w, float4 v) {
    return fmaf(w.x, v.x, fmaf(w.y, v.y, fmaf(w.z, v.z, fmaf(w.w, v.w, s))));
}

// ---------- K1: wts chunk (20 a's = 480 cells) + fused feature-stats ----------
// grid 3072 = (bn, chunk); accum[b][slot][c][2] gets atomic {sum f, sum f^2}.
__launch_bounds__(256)
__global__ void k_wts(const float* __restrict__ frag, const float* __restrict__ clouds,
                      const float* __restrict__ kernels, const float* __restrict__ W,
                      float* __restrict__ wts, float* __restrict__ accum) {
    int bx = blockIdx.x;
    int chunk = bx % 3;
    int bn = bx / 3;
    int b = bn >> 9, n = bn & (NC - 1);
    int tid = threadIdx.x, wave = tid >> 6, lane = tid & 63;
    __shared__ float4 spl[M];
    __shared__ int wcnt[16];
    __shared__ __align__(16) float swl[512];  // chunk wts (480 used)

    // per-thread cell constants
    int lc0 = tid, lc1 = tid + 256;
    float4 kc0, kc1;
    {
        int cells[2] = {chunk * CCELLS + lc0, chunk * CCELLS + lc1};
        bool vld[2] = {true, lc1 < CCELLS};
        float4* kcs[2] = {&kc0, &kc1};
        #pragma unroll
        for (int q = 0; q < 2; ++q) {
            if (vld[q]) {
                int cell = cells[q];
                int a = cell / KS, k = cell - a * KS;
                const float* kp = kernels + (size_t)(k * NA + a) * 3;
                float kx = kp[0], ky = kp[1], kz = kp[2];
                float k2 = kx * kx + ky * ky + kz * kz;
                *kcs[q] = make_float4(kx * (2.0f * LSCALE), ky * (2.0f * LSCALE),
                                      kz * (2.0f * LSCALE), -k2 * LSCALE);
            } else {
                *kcs[q] = make_float4(0.f, 0.f, 0.f, -1e30f);  // hw exp2 -> 0
            }
        }
    }

    float cx = clouds[b * 3 * NC + n];
    float cy = clouds[b * 3 * NC + NC + n];
    float cz = clouds[b * 3 * NC + 2 * NC + n];

    float dx[4], dy[4], dz[4], ei[4];
    int pos[4];
    bool pr[4];
    unsigned long long lmask = (1ull << lane) - 1ull;
    #pragma unroll
    for (int j = 0; j < 4; ++j) {
        int m = tid + j * 256;
        dx[j] = frag[3 * m]     - cx;
        dy[j] = frag[3 * m + 1] - cy;
        dz[j] = frag[3 * m + 2] - cz;
        // match jnp's non-contracted sum of squares (mask boundary exactness)
        float s = __fmul_rn(dx[j], dx[j]);
        s = __fadd_rn(s, __fmul_rn(dy[j], dy[j]));
        s = __fadd_rn(s, __fmul_rn(dz[j], dz[j]));
        pr[j] = s < R2;
        ei[j] = __builtin_amdgcn_exp2f(-s * LSCALE);
        unsigned long long mk = __ballot(pr[j]);
        pos[j] = __popcll(mk & lmask);
        if (lane == 0) wcnt[j * 4 + wave] = __popcll(mk);
    }
    __syncthreads();
    int run = 0, base[4];
    #pragma unroll
    for (int t2 = 0; t2 < 16; ++t2) {
        if ((t2 & 3) == wave) base[t2 >> 2] = run;
        run += wcnt[t2];
    }
    int cnt = run;
    #pragma unroll
    for (int j = 0; j < 4; ++j)
        if (pr[j]) spl[base[j] + pos[j]] = make_float4(dx[j], dy[j], dz[j], ei[j]);
    __syncthreads();

    float acc0 = 0.f, acc1 = 0.f;
    #pragma unroll 4
    for (int i = 0; i < cnt; ++i) {
        float4 p = spl[i];  // broadcast ds_read_b128; p.w = exp2(-d2*L)
        float a0 = fmaf(p.x, kc0.x, fmaf(p.y, kc0.y, fmaf(p.z, kc0.z, kc0.w)));
        float a1 = fmaf(p.x, kc1.x, fmaf(p.y, kc1.y, fmaf(p.z, kc1.z, kc1.w)));
        acc0 = fmaf(__builtin_amdgcn_exp2f(a0), p.w, acc0);
        acc1 = fmaf(__builtin_amdgcn_exp2f(a1), p.w, acc1);
    }

    float inv = 1.0f / (float)(cnt + 1);
    float w0 = acc0 * inv, w1 = acc1 * inv;
    float* wrow = wts + (size_t)bn * CELLS + chunk * CCELLS;
    wrow[lc0] = w0;
    swl[lc0] = w0;
    if (lc1 < CCELLS) { wrow[lc1] = w1; swl[lc1] = w1; }
    __syncthreads();

    // fused feature stats over this chunk's 20 a's: f = W[c]·v[a], accumulate
    int c = tid >> 1, ah = tid & 1;
    float4 wr[6];
    {
        const float4* W4 = (const float4*)(W + c * KS);
        #pragma unroll
        for (int j = 0; j < 6; ++j) wr[j] = W4[j];
    }
    float fs = 0.f, fs2 = 0.f;
    #pragma unroll
    for (int i = 0; i < 10; ++i) {
        const float4* v4 = (const float4*)(swl + (ah * 10 + i) * KS);
        float f = 0.f;
        #pragma unroll
        for (int j = 0; j < 6; ++j) f = dot4acc(f, wr[j], v4[j]);
        fs += f;
        fs2 = fmaf(f, f, fs2);
    }
    fs  += __shfl_xor(fs, 1);
    fs2 += __shfl_xor(fs2, 1);
    if (ah == 0) {
        int slot = bx & (NSLOT - 1);
        float* ap = accum + (((size_t)(b * NSLOT + slot) * CO + c) * 2);
        atomicAdd(&ap[0], fs);
        atomicAdd(&ap[1], fs2);
    }
}

// ---------- K2: per (bn, c-half) block; stats reduce + normalize + store ----------
// grid 2048 = bn*2 + ch; each block: 64 c's x 60 a's for one (b,n).
__launch_bounds__(256)
__global__ void k_out(const float* __restrict__ wts, const float* __restrict__ W,
                      const float* __restrict__ accum, const float* __restrict__ clouds,
                      const float* __restrict__ anchors, float* __restrict__ out) {
    int bid = blockIdx.x;
    int bn = bid >> 1, ch = bid & 1;
    int b = bn >> 9, n = bn & (NC - 1);
    int tid = threadIdx.x, wave = tid >> 6, lane = tid & 63;
    __shared__ __align__(16) float wl[CELLS];     // 5,760 B
    __shared__ float fl[64 * FLP];                // 15,616 B
    __shared__ float4 sred[256];                  // 4,096 B
    __shared__ float2 sst[64];

    // passthrough outputs (first 15 blocks)
    if (bid < 12) {
        int i = bid * 256 + tid;
        out[i] = clouds[i];
    } else if (bid < 15) {
        int i = (bid - 12) * 256 + tid;
        if (i < 540) out[ANCH_OFF + i] = anchors[i];
    }

    // wl: this bn's 1440 wts
    {
        const float4* src = (const float4*)(wts + (size_t)bn * CELLS);
        float4* wl4 = (float4*)wl;
        wl4[tid] = src[tid];
        if (tid < 104) wl4[tid + 256] = src[tid + 256];
    }

    // sred: this half's 32 c-pairs; thread (sg=tid>>5, cp=tid&31) sums 4 slots
    {
        int cp = tid & 31, sg = tid >> 5;
        const float4* A4 = (const float4*)accum;
        float4 r = make_float4(0.f, 0.f, 0.f, 0.f);
        #pragma unroll
        for (int s = 0; s < 4; ++s) {
            float4 v = A4[((size_t)(b * NSLOT + sg * 4 + s)) * 64 + ch * 32 + cp];
            r.x += v.x; r.y += v.y; r.z += v.z; r.w += v.w;
        }
        sred[tid] = r;
    }
    __syncthreads();

    if (tid < 32) {  // finalize stats for c-pair (ch*32 + tid) -> local c 2t, 2t+1
        float4 r = make_float4(0.f, 0.f, 0.f, 0.f);
        #pragma unroll
        for (int g = 0; g < 8; ++g) {
            float4 v = sred[tid + 32 * g];
            r.x += v.x; r.y += v.y; r.z += v.z; r.w += v.w;
        }
        const float invN = 1.0f / NTOT;
        float mu0 = r.x * invN;
        float var0 = fmaxf(fmaf(-mu0, mu0, r.y * invN), 0.f);
        float mu1 = r.z * invN;
        float var1 = fmaxf(fmaf(-mu1, mu1, r.w * invN), 0.f);
        sst[2 * tid]     = make_float2(mu0, rsqrtf(var0 + 1e-5f));
        sst[2 * tid + 1] = make_float2(mu1, rsqrtf(var1 + 1e-5f));
    }

    // W row for this thread's c
    int c_loc = tid >> 2, aq = tid & 3;
    int c = ch * 64 + c_loc;
    float4 wr[6];
    {
        const float4* W4 = (const float4*)(W + c * KS);
        #pragma unroll
        for (int j = 0; j < 6; ++j) wr[j] = W4[j];
    }
    __syncthreads();
    float2 st = sst[c_loc];

    // compute 15 a's for (c_loc, aq)
    #pragma unroll
    for (int i = 0; i < 15; ++i) {
        int a = aq * 15 + i;
        const float4* v4 = (const float4*)(wl + a * KS);
        float f = 0.f;
        #pragma unroll
        for (int j = 0; j < 6; ++j) f = dot4acc(f, wr[j], v4[j]);
        fl[c_loc * FLP + a] = fmaxf((f - st.x) * st.y, 0.f);
    }
    __syncthreads();

    // stores: wave w stores local c rows [w*16, w*16+16), 240 B each
    #pragma unroll 4
    for (int i = 0; i < 16; ++i) {
        int cl = wave * 16 + i;
        if (lane < NA)
            out[FEAT_OFF + (((size_t)(b * CO + ch * 64 + cl)) * NC + n) * NA + lane]
                = fl[cl * FLP + lane];
    }
}

extern "C" void kernel_launch(void* const* d_in, const int* in_sizes, int n_in,
                              void* d_out, int out_size, void* d_ws, size_t ws_size,
                              hipStream_t stream) {
    const float* frag    = (const float*)d_in[0];
    const float* clouds  = (const float*)d_in[1];
    const float* kernels = (const float*)d_in[2];
    const float* W       = (const float*)d_in[3];
    const float* anchors = (const float*)d_in[4];
    float* out = (float*)d_out;

    char* ws = (char*)d_ws;
    float* wts   = (float*)(ws);                 // 1024*1440*4 = 5,898,240 B
    float* accum = (float*)(ws + 5898240);       // 2*32*128*2*4 = 65,536 B

    hipMemsetAsync(accum, 0, 2 * NSLOT * CO * 2 * sizeof(float), stream);
    k_wts<<<3 * NB * NC, 256, 0, stream>>>(frag, clouds, kernels, W, wts, accum);
    k_out<<<2 * NB * NC, 256, 0, stream>>>(wts, W, accum, clouds, anchors, out);
}